// Round 9
// baseline (302.685 us; speedup 1.0000x reference)
//
#include <hip/hip_runtime.h>
#include <math.h>

// SSIM (16,3,512,512) fp32, 11x11 separable Gaussian, VALID -> per-batch mean [16].
//
// Round-9: round-6 barrier-free per-wave streaming, re-budgeted for 4 waves/SIMD.
//  - Each wave owns a 128-output-col strip (2 cols/thread) and stages its own
//    rows via global_load_lds; per-wave vmcnt(24) is the only synchronization.
//  - LDS row ring cut to 8 slots (slot = klin & 7, block-uniform SALU) ->
//    38.9 KB -> 4 blocks/CU. CH_OUT=24 (21 chunks) -> 4032 waves ~ 3.94/SIMD.
//  - __launch_bounds__(256,4): hard 128-reg budget so the 88-float ring stays
//    in arch VGPRs (no AGPR shuffle bloat, no occupancy loss on unified file).
//  - 4-channel register ring {r,d,rr+dd,rd} x 2 cols, all indices static.
//  - 255x scaling cancels: C1 = 1e-4, C2 = 9e-4 on [0,1] data.

#define WSZ 11
#define IMG 512
#define OSZ 502
#define NT  256
#define CH_OUT 24
#define NCHUNK 21        // 21*24 = 504 >= 502
#define NSLOT 8          // LDS row-ring depth (power of 2)
#define LA 6             // lookahead rows

struct WinArg { float w[WSZ]; };

typedef const __attribute__((address_space(1))) unsigned int* gp_t;
typedef __attribute__((address_space(3))) unsigned int* sp_t;

#define C1V 1.0e-4f
#define C2V 9.0e-4f

__global__ __launch_bounds__(NT, 4) void ssim_ws4(
    const float* __restrict__ rawp, const float* __restrict__ dstp,
    float* __restrict__ out, WinArg wa, float inv_n)
{
    // waves 0-2: 8 slots x 80 float4 (640 f4); wave 3: 8 x 64 (512 f4)
    __shared__ float4 srow[2432];            // 38912 B -> 4 blocks/CU
    __shared__ float wred[NT / 64];

    const int tid  = threadIdx.x;
    const int lane = tid & 63;
    const int wave = tid >> 6;
    const int chunk = blockIdx.x;
    const int img   = blockIdx.y;

    const int o0    = chunk * CH_OUT;
    const int olim  = min(o0 + CH_OUT, OSZ);
    const int rlast = min(o0 + CH_OUT + WSZ - 2, IMG - 1);
    const int NR    = rlast - o0 + 1;        // 34 (32 for last chunk)

    const bool w3     = (wave == 3);
    const int  nch    = w3 ? 4 : 5;          // DMA chunks per row (wave-uniform)
    const int  slotf4 = w3 ? 64 : 80;        // float4 per slot (wave-uniform)
    float4* region = srow + wave * 640;      // wave 3 -> 1920, uses 512 f4
    const int  rl     = (w3 && lane > 58) ? 58 : lane;   // read clamp
    const bool active = !(w3 && lane > 58);

    const size_t ibase = (size_t)img * (size_t)(IMG * IMG);
    // lane parity -> channel; (lane>>1) -> col within 32-col chunk
    const float* lane_base = ((lane & 1) ? dstp : rawp) + ibase
                           + (size_t)(wave * 128 + (lane >> 1));

#define STAGE(ROW, SLOT)                                                       \
    {                                                                          \
        const float* _s = lane_base + (size_t)(ROW) * IMG;                     \
        float* _d = (float*)(region + (SLOT) * slotf4);                        \
        _Pragma("unroll")                                                      \
        for (int _c = 0; _c < 5; ++_c) {                                       \
            if (_c < nch)                                                      \
                __builtin_amdgcn_global_load_lds(                              \
                    (gp_t)(const void*)(_s + 32 * _c),                         \
                    (sp_t)(void*)(_d + 64 * _c), 4, 0, 0);                     \
        }                                                                      \
    }

    float hs[WSZ][4][2];                     // ring: [slot][{r,d,rr+dd,rd}][col]
    float acc = 0.0f;

    // prologue: rows 0..LA-1 in flight (slots 0..5)
#pragma unroll
    for (int r = 0; r < LA; ++r) STAGE(o0 + r, r)

#pragma unroll 1
    for (int rr = 0; rr < NR; rr += WSZ) {
#pragma unroll
        for (int k = 0; k < WSZ; ++k) {
            const int klin = rr + k;
            if (klin < NR) {                 // block-uniform
                // stage row klin+LA (clamped tail restage lands in dead slot)
                {
                    int rs = klin + LA; if (rs > NR - 1) rs = NR - 1;
                    STAGE(o0 + rs, (klin + LA) & (NSLOT - 1))
                }
                // per-wave wait: row klin's loads complete
                // (waves 0-2: <=35 outstanding, need <=30; wave 3: <=28, need <=24)
                asm volatile("s_waitcnt vmcnt(24)" ::: "memory");

                float4 q[6];
                {
                    const float4* rp = region + (klin & (NSLOT - 1)) * slotf4 + rl;
#pragma unroll
                    for (int j = 0; j < 6; ++j) q[j] = rp[j];
                }

                // ---- H-pass, 2 cols, element-shared prep ----
                float s1a = 0.f, s2a = 0.f, s3a = 0.f, s4a = 0.f;
                float s1b = 0.f, s2b = 0.f, s3b = 0.f, s4b = 0.f;
#pragma unroll
                for (int e = 0; e < 12; ++e) {
                    const float r = (e & 1) ? q[e >> 1].z : q[e >> 1].x;
                    const float d = (e & 1) ? q[e >> 1].w : q[e >> 1].y;
                    const float sq = fmaf(d, d, r * r);
                    const float p  = r * d;
                    if (e < 11) {            // col a tap e
                        const float w_ = wa.w[e];
                        s1a = fmaf(w_, r, s1a);
                        s2a = fmaf(w_, d, s2a);
                        s3a = fmaf(w_, sq, s3a);
                        s4a = fmaf(w_, p,  s4a);
                    }
                    if (e >= 1) {            // col b tap e-1
                        const float w_ = wa.w[e - 1];
                        s1b = fmaf(w_, r, s1b);
                        s2b = fmaf(w_, d, s2b);
                        s3b = fmaf(w_, sq, s3b);
                        s4b = fmaf(w_, p,  s4b);
                    }
                }
                hs[klin % WSZ][0][0] = s1a; hs[klin % WSZ][1][0] = s2a;
                hs[klin % WSZ][2][0] = s3a; hs[klin % WSZ][3][0] = s4a;
                hs[klin % WSZ][0][1] = s1b; hs[klin % WSZ][1][1] = s2b;
                hs[klin % WSZ][2][1] = s3b; hs[klin % WSZ][3][1] = s4b;

                // ---- V-pass + SSIM ----
                const int o = o0 + klin - (WSZ - 1);
                if (klin >= WSZ - 1 && o < olim && active) {
                    float m1a = 0.f, m2a = 0.f, m3a = 0.f, m4a = 0.f;
                    float m1b = 0.f, m2b = 0.f, m3b = 0.f, m4b = 0.f;
#pragma unroll
                    for (int i = 0; i < WSZ; ++i) {
                        const int s = (klin + 1 + i) % WSZ;  // static after unroll
                        const float wi = wa.w[i];
                        m1a = fmaf(wi, hs[s][0][0], m1a);
                        m2a = fmaf(wi, hs[s][1][0], m2a);
                        m3a = fmaf(wi, hs[s][2][0], m3a);
                        m4a = fmaf(wi, hs[s][3][0], m4a);
                        m1b = fmaf(wi, hs[s][0][1], m1b);
                        m2b = fmaf(wi, hs[s][1][1], m2b);
                        m3b = fmaf(wi, hs[s][2][1], m3b);
                        m4b = fmaf(wi, hs[s][3][1], m4b);
                    }
                    {
                        const float q1 = m1a * m1a, q2 = m2a * m2a, mm = m1a * m2a;
                        const float num = (2.f * mm + C1V) * (2.f * (m4a - mm) + C2V);
                        const float den = (q1 + q2 + C1V) * (((m3a - q1) - q2) + C2V);
                        acc += num * __builtin_amdgcn_rcpf(den);
                    }
                    {
                        const float q1 = m1b * m1b, q2 = m2b * m2b, mm = m1b * m2b;
                        const float num = (2.f * mm + C1V) * (2.f * (m4b - mm) + C2V);
                        const float den = (q1 + q2 + C1V) * (((m3b - q1) - q2) + C2V);
                        acc += num * __builtin_amdgcn_rcpf(den);
                    }
                }
            }
        }
    }
#undef STAGE

    // ---- block reduction -> one atomicAdd per block ----
#pragma unroll
    for (int off = 32; off > 0; off >>= 1) acc += __shfl_down(acc, off, 64);
    if (lane == 0) wred[wave] = acc;
    __syncthreads();
    if (tid == 0) {
        const float tot = (wred[0] + wred[1]) + (wred[2] + wred[3]);
        atomicAdd(out + img / 3, tot * inv_n);
    }
}

extern "C" void kernel_launch(void* const* d_in, const int* in_sizes, int n_in,
                              void* d_out, int out_size, void* d_ws, size_t ws_size,
                              hipStream_t stream) {
    const float* raw = (const float*)d_in[0];
    const float* dst = (const float*)d_in[1];
    float* out = (float*)d_out;

    hipMemsetAsync(out, 0, (size_t)out_size * sizeof(float), stream);

    WinArg wa;
    double g[WSZ], s = 0.0;
    for (int i = 0; i < WSZ; ++i) {
        double ax = (double)i - (double)(WSZ - 1) / 2.0;
        g[i] = exp(-(ax * ax) / (2.0 * 1.5 * 1.5));
        s += g[i];
    }
    for (int i = 0; i < WSZ; ++i) wa.w[i] = (float)(g[i] / s);

    const float inv_n = (float)(1.0 / (3.0 * (double)OSZ * (double)OSZ));

    dim3 grid(NCHUNK, 48);
    ssim_ws4<<<grid, NT, 0, stream>>>(raw, dst, out, wa, inv_n);
}

// Round 10
// 105.358 us; speedup vs baseline: 2.8729x; 2.8729x over previous
//
#include <hip/hip_runtime.h>
#include <math.h>

// SSIM (16,3,512,512) fp32, 11x11 separable Gaussian, VALID -> per-batch mean [16].
//
// Round-10: 1 col/thread (44-float ring -> <=128 unified regs -> 4 waves/SIMD),
// barrier-free fully-independent waves.
//  - Block = 4 waves. Wave w: strip = w>>1 (128 cols), parity P = w&1
//    (cols cb+2l+P) -> float4 window q[l..l+5], extraction static per wave.
//  - Each wave stages its own private LDS copy of its strip (channel-
//    interleaved, 5 chunks x 32 cols via global_load_lds w=4); duplicate
//    loads of a strip by the pair wave are L2 hits (HBM unaffected).
//  - No s_barrier in main loop; per-wave counted vmcnt only (30 / 24 exact).
//  - LDS = 4 x 8 slots x 1280 B = 40960 B exactly -> 4 blocks/CU; reduction
//    scratch aliased onto srow after a final barrier.
//  - 255x scaling cancels: C1 = 1e-4, C2 = 9e-4 on [0,1] data.

#define WSZ 11
#define IMG 512
#define OSZ 502
#define NT  256
#define CH_OUT 46
#define NCHUNK 11        // 11*46 = 506 >= 502
#define NSLOT 8          // LDS row-ring depth (power of 2)
#define LA 6             // lookahead rows
#define SLOTF4 80        // float4 per slot (160 cols x 2ch interleaved)

struct WinArg { float w[WSZ]; };

typedef const __attribute__((address_space(1))) unsigned int* gp_t;
typedef __attribute__((address_space(3))) unsigned int* sp_t;

#define C1V 1.0e-4f
#define C2V 9.0e-4f

__global__ __launch_bounds__(NT, 4) void ssim_solo(
    const float* __restrict__ rawp, const float* __restrict__ dstp,
    float* __restrict__ out, WinArg wa, float inv_n)
{
    __shared__ float4 srow[4 * NSLOT * SLOTF4];   // 40960 B exactly

    const int tid  = threadIdx.x;
    const int lane = tid & 63;
    const int wave = tid >> 6;
    const int half  = blockIdx.x & 1;             // 0: cols 0..255, 1: 256..501
    const int chunk = blockIdx.x >> 1;
    const int img   = blockIdx.y;

    const int strip = wave >> 1;                  // strip within half
    const int P     = wave & 1;                   // column parity
    const int cb    = half * 256 + strip * 128;   // strip base col (0/128/256/384)

    const int o0    = chunk * CH_OUT;
    const int olim  = min(o0 + CH_OUT, OSZ);
    const int rlast = min(o0 + CH_OUT + WSZ - 2, IMG - 1);
    const int NR    = rlast - o0 + 1;             // 56 (52 for last chunk)

    const bool tail = (cb == 384);                // 4-chunk strip
    const int  nch  = tail ? 4 : 5;
    float4* region  = srow + wave * (NSLOT * SLOTF4);
    const bool active = (!tail) || (lane <= 58);  // col = cb+2l+P <= 501
    const int  rl     = active ? lane : 58;       // clamped read index

    const size_t ibase = (size_t)img * (size_t)(IMG * IMG);
    // staging: lane parity -> channel, (lane>>1) -> col within 32-col chunk
    const float* lane_base = ((lane & 1) ? dstp : rawp) + ibase
                           + (size_t)(cb + (lane >> 1));

#define STAGE(ROW, SLOT)                                                       \
    {                                                                          \
        const float* _s = lane_base + (size_t)(ROW) * IMG;                     \
        float* _d = (float*)(region + (SLOT) * SLOTF4);                        \
        _Pragma("unroll")                                                      \
        for (int _c = 0; _c < 5; ++_c) {                                       \
            if (_c < nch)                                                      \
                __builtin_amdgcn_global_load_lds(                              \
                    (gp_t)(const void*)(_s + 32 * _c),                         \
                    (sp_t)(void*)(_d + 64 * _c), 4, 0, 0);                     \
        }                                                                      \
    }

    float hs[WSZ][4];                             // ring: [slot][{r,d,rr+dd,rd}]
    float acc = 0.0f;

    // prologue: rows 0..LA-1 in flight (slots 0..5)
#pragma unroll
    for (int r = 0; r < LA; ++r) STAGE(o0 + r, r)

#pragma unroll 1
    for (int rr = 0; rr < NR; rr += WSZ) {
#pragma unroll
        for (int k = 0; k < WSZ; ++k) {
            const int klin = rr + k;
            if (klin < NR) {                      // block-uniform
                // stage row klin+LA (clamped tail restage lands in dead slot)
                {
                    int rs = klin + LA; if (rs > NR - 1) rs = NR - 1;
                    STAGE(o0 + rs, (klin + LA) & (NSLOT - 1))
                }
                // per-wave exact wait: rows klin+1..klin+LA may stay in flight
                if (nch == 5) asm volatile("s_waitcnt vmcnt(30)" ::: "memory");
                else          asm volatile("s_waitcnt vmcnt(24)" ::: "memory");

                float4 q[6];
                {
                    const float4* rp = region + (klin & (NSLOT - 1)) * SLOTF4 + rl;
#pragma unroll
                    for (int j = 0; j < 6; ++j) q[j] = rp[j];
                }

                // ---- H-pass: one column, elements P..P+10 (static) ----
#define HPASS(PP)                                                              \
                {                                                              \
                    float a1 = 0.f, a2 = 0.f, a3 = 0.f, a4 = 0.f;              \
                    _Pragma("unroll")                                          \
                    for (int j = 0; j < WSZ; ++j) {                            \
                        const int e = (PP) + j;                                \
                        const float wj = wa.w[j];                              \
                        const float r = (e & 1) ? q[e >> 1].z : q[e >> 1].x;   \
                        const float d = (e & 1) ? q[e >> 1].w : q[e >> 1].y;   \
                        a1 = fmaf(wj, r, a1);                                  \
                        a2 = fmaf(wj, d, a2);                                  \
                        a3 = fmaf(wj, fmaf(d, d, r * r), a3);                  \
                        a4 = fmaf(wj, r * d, a4);                              \
                    }                                                          \
                    hs[k][0] = a1; hs[k][1] = a2; hs[k][2] = a3; hs[k][3] = a4;\
                }
                if (P == 0) { HPASS(0) } else { HPASS(1) }
#undef HPASS

                // ---- V-pass + SSIM ----
                const int o = o0 + klin - (WSZ - 1);
                if (klin >= WSZ - 1 && o < olim && active) {
                    float m1 = 0.f, m2 = 0.f, m3 = 0.f, m4 = 0.f;
#pragma unroll
                    for (int i = 0; i < WSZ; ++i) {
                        const int s = (k + 1 + i) % WSZ;   // static after unroll
                        const float wi = wa.w[i];
                        m1 = fmaf(wi, hs[s][0], m1);
                        m2 = fmaf(wi, hs[s][1], m2);
                        m3 = fmaf(wi, hs[s][2], m3);
                        m4 = fmaf(wi, hs[s][3], m4);
                    }
                    const float q1 = m1 * m1, q2 = m2 * m2, mm = m1 * m2;
                    const float num = (2.f * mm + C1V) * (2.f * (m4 - mm) + C2V);
                    const float den = (q1 + q2 + C1V) * (((m3 - q1) - q2) + C2V);
                    acc += num * __builtin_amdgcn_rcpf(den);
                }
            }
        }
    }
#undef STAGE

    // ---- block reduction (wred aliased onto srow after all waves finish) ----
#pragma unroll
    for (int off = 32; off > 0; off >>= 1) acc += __shfl_down(acc, off, 64);
    __syncthreads();                      // everyone done with srow
    float* wred = (float*)srow;
    if (lane == 0) wred[wave] = acc;
    __syncthreads();
    if (tid == 0) {
        const float tot = (wred[0] + wred[1]) + (wred[2] + wred[3]);
        atomicAdd(out + img / 3, tot * inv_n);
    }
}

extern "C" void kernel_launch(void* const* d_in, const int* in_sizes, int n_in,
                              void* d_out, int out_size, void* d_ws, size_t ws_size,
                              hipStream_t stream) {
    const float* raw = (const float*)d_in[0];
    const float* dst = (const float*)d_in[1];
    float* out = (float*)d_out;

    hipMemsetAsync(out, 0, (size_t)out_size * sizeof(float), stream);

    WinArg wa;
    double g[WSZ], s = 0.0;
    for (int i = 0; i < WSZ; ++i) {
        double ax = (double)i - (double)(WSZ - 1) / 2.0;
        g[i] = exp(-(ax * ax) / (2.0 * 1.5 * 1.5));
        s += g[i];
    }
    for (int i = 0; i < WSZ; ++i) wa.w[i] = (float)(g[i] / s);

    const float inv_n = (float)(1.0 / (3.0 * (double)OSZ * (double)OSZ));

    dim3 grid(2 * NCHUNK, 48);
    ssim_solo<<<grid, NT, 0, stream>>>(raw, dst, out, wa, inv_n);
}

// Round 11
// 94.985 us; speedup vs baseline: 3.1866x; 1.1092x over previous
//
#include <hip/hip_runtime.h>
#include <math.h>

// SSIM (16,3,512,512) fp32, 11x11 separable Gaussian, VALID -> per-batch mean [16].
//
// Round-11: 2-col/thread ring at 3 waves/SIMD.
//  - 128-thread blocks = 2 independent waves; wave w owns strip 2*(bx&1)+w
//    (128 output cols, 2 cols/thread). No s_barrier in the main loop.
//  - 2-row inner steps in 24-row unrolled groups: LDS slot (klin%8) and ring
//    slot (klin%12) are compile-time static (24 % 8 == 24 % 12 == 0).
//  - Per step: STAGE rows klin+6,klin+7 -> vmcnt(30/24 exact) -> read qA ->
//    H(A) -> read qB -> V(A)+SSIM (covers qB latency) -> H(B) -> V(B)+SSIM.
//  - Ring 12x4x2 = 96 floats + one 24-float q -> peak ~150 regs, under the
//    __launch_bounds__(128,3) cap (~168) -> 12 waves/CU; grid 1536 = 6
//    blocks/CU resident exactly (LDS 20.5 KB).
//  - 255x scaling cancels: C1 = 1e-4, C2 = 9e-4 on [0,1] data.

#define WSZ 11
#define IMG 512
#define OSZ 502
#define NT  128
#define CH_OUT 32
#define NCHUNK 16        // 16*32 >= 502
#define RING 12          // register ring depth (2 | 12, static under 24-unroll)
#define NSLOT 8          // LDS row-ring depth
#define SLOTF4 80        // float4 per slot (160 cols, channel-interleaved)

struct WinArg { float w[WSZ]; };

typedef const __attribute__((address_space(1))) unsigned int* gp_t;
typedef __attribute__((address_space(3))) unsigned int* sp_t;

#define C1V 1.0e-4f
#define C2V 9.0e-4f

__global__ __launch_bounds__(NT, 3) void ssim_duo(
    const float* __restrict__ rawp, const float* __restrict__ dstp,
    float* __restrict__ out, WinArg wa, float inv_n)
{
    __shared__ float4 srow[2 * NSLOT * SLOTF4];   // 20480 B
    __shared__ float wred[2];

    const int tid  = threadIdx.x;
    const int lane = tid & 63;
    const int wave = tid >> 6;
    const int sp    = blockIdx.x & 1;             // strip pair
    const int chunk = blockIdx.x >> 1;
    const int img   = blockIdx.y;

    const int strip = sp * 2 + wave;              // 0..3
    const int cb    = strip * 128;                // base output col

    const int o0    = chunk * CH_OUT;
    const int olim  = min(o0 + CH_OUT, OSZ);
    const int rlast = min(o0 + CH_OUT + WSZ - 2, IMG - 1);
    const int NR    = rlast - o0 + 1;             // 42 (32 last chunk), even

    const bool tail   = (strip == 3);             // 118 outputs, 4 chunks
    const int  nch    = tail ? 4 : 5;
    float4* region    = srow + wave * (NSLOT * SLOTF4);
    const bool active = (!tail) || (lane <= 58);
    const int  rl     = active ? lane : 58;

    const size_t ibase = (size_t)img * (size_t)(IMG * IMG);
    // staging: lane parity -> channel, (lane>>1) -> col within 32-col chunk
    const float* lane_base = ((lane & 1) ? dstp : rawp) + ibase
                           + (size_t)(cb + (lane >> 1));

#define STAGE(ROW, SLOT)                                                       \
    {                                                                          \
        const float* _s = lane_base + (size_t)(ROW) * IMG;                     \
        float* _d = (float*)(region + (SLOT) * SLOTF4);                        \
        _Pragma("unroll")                                                      \
        for (int _c = 0; _c < 5; ++_c) {                                       \
            if (_c < nch)                                                      \
                __builtin_amdgcn_global_load_lds(                              \
                    (gp_t)(const void*)(_s + 32 * _c),                         \
                    (sp_t)(void*)(_d + 64 * _c), 4, 0, 0);                     \
        }                                                                      \
    }

    // H-pass on window QQ (12 elements, 2 cols element-shared) -> ring slot KS
#define HPASS(QQ, KS)                                                          \
    {                                                                          \
        float s1a = 0.f, s2a = 0.f, s3a = 0.f, s4a = 0.f;                      \
        float s1b = 0.f, s2b = 0.f, s3b = 0.f, s4b = 0.f;                      \
        _Pragma("unroll")                                                      \
        for (int e = 0; e < 12; ++e) {                                         \
            const float r = (e & 1) ? QQ[e >> 1].z : QQ[e >> 1].x;             \
            const float d = (e & 1) ? QQ[e >> 1].w : QQ[e >> 1].y;             \
            const float sq = fmaf(d, d, r * r);                                \
            const float p  = r * d;                                            \
            if (e < 11) {                                                      \
                const float w_ = wa.w[e];                                      \
                s1a = fmaf(w_, r, s1a);  s2a = fmaf(w_, d, s2a);               \
                s3a = fmaf(w_, sq, s3a); s4a = fmaf(w_, p, s4a);               \
            }                                                                  \
            if (e >= 1) {                                                      \
                const float w_ = wa.w[e - 1];                                  \
                s1b = fmaf(w_, r, s1b);  s2b = fmaf(w_, d, s2b);               \
                s3b = fmaf(w_, sq, s3b); s4b = fmaf(w_, p, s4b);               \
            }                                                                  \
        }                                                                      \
        hs[KS][0][0] = s1a; hs[KS][1][0] = s2a;                                \
        hs[KS][2][0] = s3a; hs[KS][3][0] = s4a;                                \
        hs[KS][0][1] = s1b; hs[KS][1][1] = s2b;                                \
        hs[KS][2][1] = s3b; hs[KS][3][1] = s4b;                                \
    }

    // V-pass + SSIM for output row; ring slots (KOFF+i)%RING, i=0..10
#define VPASS(KOFF)                                                            \
    {                                                                          \
        float m1a = 0.f, m2a = 0.f, m3a = 0.f, m4a = 0.f;                      \
        float m1b = 0.f, m2b = 0.f, m3b = 0.f, m4b = 0.f;                      \
        _Pragma("unroll")                                                      \
        for (int i = 0; i < WSZ; ++i) {                                        \
            const int s = ((KOFF) + i) % RING;                                 \
            const float wi = wa.w[i];                                          \
            m1a = fmaf(wi, hs[s][0][0], m1a); m2a = fmaf(wi, hs[s][1][0], m2a);\
            m3a = fmaf(wi, hs[s][2][0], m3a); m4a = fmaf(wi, hs[s][3][0], m4a);\
            m1b = fmaf(wi, hs[s][0][1], m1b); m2b = fmaf(wi, hs[s][1][1], m2b);\
            m3b = fmaf(wi, hs[s][2][1], m3b); m4b = fmaf(wi, hs[s][3][1], m4b);\
        }                                                                      \
        {                                                                      \
            const float q1 = m1a * m1a, q2 = m2a * m2a, mm = m1a * m2a;        \
            const float num = (2.f * mm + C1V) * (2.f * (m4a - mm) + C2V);     \
            const float den = (q1 + q2 + C1V) * (((m3a - q1) - q2) + C2V);     \
            acc += num * __builtin_amdgcn_rcpf(den);                           \
        }                                                                      \
        {                                                                      \
            const float q1 = m1b * m1b, q2 = m2b * m2b, mm = m1b * m2b;        \
            const float num = (2.f * mm + C1V) * (2.f * (m4b - mm) + C2V);     \
            const float den = (q1 + q2 + C1V) * (((m3b - q1) - q2) + C2V);     \
            acc += num * __builtin_amdgcn_rcpf(den);                           \
        }                                                                      \
    }

    float hs[RING][4][2];
    float acc = 0.0f;

    // prologue: rows 0..5 in flight (slots 0..5)
#pragma unroll
    for (int r = 0; r < 6; ++r) STAGE(o0 + r, r)

#pragma unroll 1
    for (int rr = 0; rr < NR; rr += 24) {
#pragma unroll
        for (int S = 0; S < 12; ++S) {
            const int klin = rr + 2 * S;          // even; klin%8=(2S)%8 etc.
            if (klin < NR) {                      // block-uniform
                // stage rows klin+6, klin+7 (clamped tail restage -> dead slot)
                {
                    int ra = klin + 6; if (ra > NR - 1) ra = NR - 1;
                    int rb = klin + 7; if (rb > NR - 1) rb = NR - 1;
                    STAGE(o0 + ra, (2 * S + 6) % NSLOT)
                    STAGE(o0 + rb, (2 * S + 7) % NSLOT)
                }
                // exact per-wave wait: rows klin, klin+1 landed
                if (nch == 5) asm volatile("s_waitcnt vmcnt(30)" ::: "memory");
                else          asm volatile("s_waitcnt vmcnt(24)" ::: "memory");

                float4 qA[6];
                {
                    const float4* rp = region + ((2 * S) % NSLOT) * SLOTF4 + rl;
#pragma unroll
                    for (int j = 0; j < 6; ++j) qA[j] = rp[j];
                }
                HPASS(qA, (2 * S) % RING)

                float4 qB[6];
                {
                    const float4* rp = region + ((2 * S + 1) % NSLOT) * SLOTF4 + rl;
#pragma unroll
                    for (int j = 0; j < 6; ++j) qB[j] = rp[j];
                }

                // V for row klin (output o = klin-10); covers qB latency
                if (klin >= WSZ - 1 && (o0 + klin - (WSZ - 1)) < olim && active)
                    VPASS(2 * S + 2)

                HPASS(qB, (2 * S + 1) % RING)

                // V for row klin+1
                if (klin + 1 >= WSZ - 1 && (o0 + klin + 1 - (WSZ - 1)) < olim && active)
                    VPASS(2 * S + 3)
            }
        }
    }
#undef STAGE
#undef HPASS
#undef VPASS

    // ---- reduction: 2 waves -> one atomicAdd per block ----
#pragma unroll
    for (int off = 32; off > 0; off >>= 1) acc += __shfl_down(acc, off, 64);
    if (lane == 0) wred[wave] = acc;
    __syncthreads();
    if (tid == 0) atomicAdd(out + img / 3, (wred[0] + wred[1]) * inv_n);
}

extern "C" void kernel_launch(void* const* d_in, const int* in_sizes, int n_in,
                              void* d_out, int out_size, void* d_ws, size_t ws_size,
                              hipStream_t stream) {
    const float* raw = (const float*)d_in[0];
    const float* dst = (const float*)d_in[1];
    float* out = (float*)d_out;

    hipMemsetAsync(out, 0, (size_t)out_size * sizeof(float), stream);

    WinArg wa;
    double g[WSZ], s = 0.0;
    for (int i = 0; i < WSZ; ++i) {
        double ax = (double)i - (double)(WSZ - 1) / 2.0;
        g[i] = exp(-(ax * ax) / (2.0 * 1.5 * 1.5));
        s += g[i];
    }
    for (int i = 0; i < WSZ; ++i) wa.w[i] = (float)(g[i] / s);

    const float inv_n = (float)(1.0 / (3.0 * (double)OSZ * (double)OSZ));

    dim3 grid(2 * NCHUNK, 48);
    ssim_duo<<<grid, NT, 0, stream>>>(raw, dst, out, wa, inv_n);
}

// Round 12
// 76.895 us; speedup vs baseline: 3.9363x; 1.2353x over previous
//
#include <hip/hip_runtime.h>
#include <math.h>

// SSIM (16,3,512,512) fp32, 11x11 separable Gaussian, VALID -> per-batch mean [16].
//
// Round-12: EXACT round-6 kernel (best: 78.6us) with ONE change:
// __launch_bounds__(256,3) -> (256,2). Theory: at budget 170 the allocator
// split the register file (84 VGPR + ~86 AGPR), parking the 88-float ring in
// AGPRs; every ring access then pays a v_accvgpr move (~96 extra VALU/row =
// the measured 1.6x instruction bloat) while still capping occupancy at
// 2-3 waves/SIMD. Budget 256 fits the whole live set in pure arch VGPRs.
//  - Each wave owns a 128-output-col strip (2 cols/thread) and stages its own
//    rows via global_load_lds; per-wave vmcnt is the only synchronization.
//  - LDS: per-wave 11-slot row ring, channel-interleaved float4(r,d,r,d).
//  - Lookahead 6 rows, counted s_waitcnt vmcnt(24) (never drained to 0).
//  - 4-channel register ring {r,d,rr+dd,rd} x 2 cols = 88 floats, static idx.
//  - 255x scaling cancels algebraically: C1 = 1e-4, C2 = 9e-4 on [0,1] data.

#define WSZ 11
#define IMG 512
#define OSZ 502
#define NT  256
#define CH_OUT 32
#define NCHUNK 16        // 16*32 >= 502
#define NSLOT 11
#define LA 6             // lookahead rows

struct WinArg { float w[WSZ]; };

typedef const __attribute__((address_space(1))) unsigned int* gp_t;
typedef __attribute__((address_space(3))) unsigned int* sp_t;

#define C1V 1.0e-4f
#define C2V 9.0e-4f

__global__ __launch_bounds__(NT, 2) void ssim_novgpr(
    const float* __restrict__ rawp, const float* __restrict__ dstp,
    float* __restrict__ out, WinArg wa, float inv_n)
{
    // waves 0-2: 11 slots x 80 float4 (880 f4 each); wave 3: 11 x 64 (704 f4)
    __shared__ float4 srow[3344];            // 53504 B
    __shared__ float wred[NT / 64];

    const int tid  = threadIdx.x;
    const int lane = tid & 63;
    const int wave = tid >> 6;
    const int chunk = blockIdx.x;
    const int img   = blockIdx.y;

    const int o0    = chunk * CH_OUT;
    const int olim  = min(o0 + CH_OUT, OSZ);
    const int rlast = min(o0 + CH_OUT + WSZ - 2, IMG - 1);
    const int NR    = rlast - o0 + 1;        // 42 (32 for last chunk)

    const bool w3     = (wave == 3);
    const int  nch    = w3 ? 4 : 5;          // DMA chunks per row (wave-uniform)
    const int  slotf4 = w3 ? 64 : 80;        // float4 per slot (wave-uniform)
    float4* region = srow + wave * 880;      // wave 3 -> 2640, uses 704 f4
    const int  rl     = (w3 && lane > 58) ? 58 : lane;   // read clamp
    const bool active = !(w3 && lane > 58);

    const size_t ibase = (size_t)img * (size_t)(IMG * IMG);
    // lane parity -> channel; (lane>>1) -> col within 32-col chunk
    const float* lane_base = ((lane & 1) ? dstp : rawp) + ibase
                           + (size_t)(wave * 128 + (lane >> 1));

#define STAGE(ROW, SLOT)                                                       \
    {                                                                          \
        const float* _s = lane_base + (size_t)(ROW) * IMG;                     \
        float* _d = (float*)(region + (SLOT) * slotf4);                        \
        _Pragma("unroll")                                                      \
        for (int _c = 0; _c < 5; ++_c) {                                       \
            if (_c < nch)                                                      \
                __builtin_amdgcn_global_load_lds(                              \
                    (gp_t)(const void*)(_s + 32 * _c),                         \
                    (sp_t)(void*)(_d + 64 * _c), 4, 0, 0);                     \
        }                                                                      \
    }

    float hs[WSZ][4][2];                     // ring: [slot][{r,d,rr+dd,rd}][col]
    float acc = 0.0f;

    // prologue: rows 0..LA-1 in flight (slots 0..5)
#pragma unroll
    for (int r = 0; r < LA; ++r) STAGE(o0 + r, r)

#pragma unroll 1
    for (int rr = 0; rr < NR; rr += WSZ) {
#pragma unroll
        for (int k = 0; k < WSZ; ++k) {
            const int klin = rr + k;
            if (klin < NR) {                 // block-uniform
                // stage row klin+LA (clamped tail restage lands in dead slot)
                {
                    int rs = klin + LA; if (rs > NR - 1) rs = NR - 1;
                    STAGE(o0 + rs, (k + LA) % NSLOT)
                }
                // per-wave wait: guarantees row klin's loads complete
                asm volatile("s_waitcnt vmcnt(24)" ::: "memory");

                float4 q[6];
                {
                    const float4* rp = region + k * slotf4 + rl;
#pragma unroll
                    for (int j = 0; j < 6; ++j) q[j] = rp[j];
                }

                // ---- H-pass, 2 cols, element-shared prep ----
                float s1a = 0.f, s2a = 0.f, s3a = 0.f, s4a = 0.f;
                float s1b = 0.f, s2b = 0.f, s3b = 0.f, s4b = 0.f;
#pragma unroll
                for (int e = 0; e < 12; ++e) {
                    const float r = (e & 1) ? q[e >> 1].z : q[e >> 1].x;
                    const float d = (e & 1) ? q[e >> 1].w : q[e >> 1].y;
                    const float sq = fmaf(d, d, r * r);
                    const float p  = r * d;
                    if (e < 11) {            // col a tap e
                        const float w_ = wa.w[e];
                        s1a = fmaf(w_, r, s1a);
                        s2a = fmaf(w_, d, s2a);
                        s3a = fmaf(w_, sq, s3a);
                        s4a = fmaf(w_, p,  s4a);
                    }
                    if (e >= 1) {            // col b tap e-1
                        const float w_ = wa.w[e - 1];
                        s1b = fmaf(w_, r, s1b);
                        s2b = fmaf(w_, d, s2b);
                        s3b = fmaf(w_, sq, s3b);
                        s4b = fmaf(w_, p,  s4b);
                    }
                }
                hs[k][0][0] = s1a; hs[k][1][0] = s2a; hs[k][2][0] = s3a; hs[k][3][0] = s4a;
                hs[k][0][1] = s1b; hs[k][1][1] = s2b; hs[k][2][1] = s3b; hs[k][3][1] = s4b;

                // ---- V-pass + SSIM ----
                const int o = o0 + klin - (WSZ - 1);
                if (klin >= WSZ - 1 && o < olim && active) {
                    float m1a = 0.f, m2a = 0.f, m3a = 0.f, m4a = 0.f;
                    float m1b = 0.f, m2b = 0.f, m3b = 0.f, m4b = 0.f;
#pragma unroll
                    for (int i = 0; i < WSZ; ++i) {
                        const int s = (k + 1 + i) % WSZ;   // static after unroll
                        const float wi = wa.w[i];
                        m1a = fmaf(wi, hs[s][0][0], m1a);
                        m2a = fmaf(wi, hs[s][1][0], m2a);
                        m3a = fmaf(wi, hs[s][2][0], m3a);
                        m4a = fmaf(wi, hs[s][3][0], m4a);
                        m1b = fmaf(wi, hs[s][0][1], m1b);
                        m2b = fmaf(wi, hs[s][1][1], m2b);
                        m3b = fmaf(wi, hs[s][2][1], m3b);
                        m4b = fmaf(wi, hs[s][3][1], m4b);
                    }
                    {
                        const float q1 = m1a * m1a, q2 = m2a * m2a, mm = m1a * m2a;
                        const float num = (2.f * mm + C1V) * (2.f * (m4a - mm) + C2V);
                        const float den = (q1 + q2 + C1V) * (((m3a - q1) - q2) + C2V);
                        acc += num * __builtin_amdgcn_rcpf(den);
                    }
                    {
                        const float q1 = m1b * m1b, q2 = m2b * m2b, mm = m1b * m2b;
                        const float num = (2.f * mm + C1V) * (2.f * (m4b - mm) + C2V);
                        const float den = (q1 + q2 + C1V) * (((m3b - q1) - q2) + C2V);
                        acc += num * __builtin_amdgcn_rcpf(den);
                    }
                }
            }
        }
    }
#undef STAGE

    // ---- block reduction -> one atomicAdd per block ----
#pragma unroll
    for (int off = 32; off > 0; off >>= 1) acc += __shfl_down(acc, off, 64);
    if (lane == 0) wred[wave] = acc;
    __syncthreads();
    if (tid == 0) {
        const float tot = (wred[0] + wred[1]) + (wred[2] + wred[3]);
        atomicAdd(out + img / 3, tot * inv_n);
    }
}

extern "C" void kernel_launch(void* const* d_in, const int* in_sizes, int n_in,
                              void* d_out, int out_size, void* d_ws, size_t ws_size,
                              hipStream_t stream) {
    const float* raw = (const float*)d_in[0];
    const float* dst = (const float*)d_in[1];
    float* out = (float*)d_out;

    hipMemsetAsync(out, 0, (size_t)out_size * sizeof(float), stream);

    WinArg wa;
    double g[WSZ], s = 0.0;
    for (int i = 0; i < WSZ; ++i) {
        double ax = (double)i - (double)(WSZ - 1) / 2.0;
        g[i] = exp(-(ax * ax) / (2.0 * 1.5 * 1.5));
        s += g[i];
    }
    for (int i = 0; i < WSZ; ++i) wa.w[i] = (float)(g[i] / s);

    const float inv_n = (float)(1.0 / (3.0 * (double)OSZ * (double)OSZ));

    dim3 grid(NCHUNK, 48);
    ssim_novgpr<<<grid, NT, 0, stream>>>(raw, dst, out, wa, inv_n);
}